// Round 5
// baseline (320.181 us; speedup 1.0000x reference)
//
#include <hip/hip_runtime.h>
#include <hip/hip_bf16.h>

#define B_ 4
#define S_ 1024
#define E_ 1024
#define H_ 16
#define D_ 64

typedef __attribute__((ext_vector_type(8))) short short8;
typedef __attribute__((ext_vector_type(4))) float f32x4;

static __device__ __forceinline__ unsigned short f2bf(float x) {
  unsigned int u = __float_as_uint(x);
  unsigned int r = u + 0x7fffu + ((u >> 16) & 1u);  // round-to-nearest-even
  return (unsigned short)(r >> 16);
}
static __device__ __forceinline__ float bf2f(unsigned short b) {
  return __uint_as_float((unsigned int)b << 16);
}

#define GL2LDS16(g, l)                                                            \
  __builtin_amdgcn_global_load_lds(                                               \
      (const __attribute__((address_space(1))) unsigned int*)(g),                 \
      (__attribute__((address_space(3))) unsigned int*)(l), 16, 0, 0)

// ---------------- mask symmetrize: msym = mask | mask^T (uint8) ----------------
__global__ __launch_bounds__(256) void mask_sym_kernel(const int* __restrict__ mask,
                                                       unsigned char* __restrict__ msym) {
  const int blk = blockIdx.x;            // B * 32 * 32 = 4096
  const int b = blk >> 10;
  const int rest = blk & 1023;
  const int i0 = (rest >> 5) << 5;
  const int j0 = (rest & 31) << 5;
  __shared__ int T[32][33];
  const int tid = threadIdx.x;
  const int ii = tid >> 3;
  const int jj4 = (tid & 7) << 2;
  const size_t bO = (size_t)b * S_ * S_;
  const int4 m2 = *(const int4*)&mask[bO + (size_t)(j0 + ii) * S_ + i0 + jj4];
  T[ii][jj4 + 0] = m2.x; T[ii][jj4 + 1] = m2.y; T[ii][jj4 + 2] = m2.z; T[ii][jj4 + 3] = m2.w;
  __syncthreads();
  const int4 m1 = *(const int4*)&mask[bO + (size_t)(i0 + ii) * S_ + j0 + jj4];
  uchar4 o;
  o.x = ((m1.x != 0) || (T[jj4 + 0][ii] != 0)) ? 1 : 0;
  o.y = ((m1.y != 0) || (T[jj4 + 1][ii] != 0)) ? 1 : 0;
  o.z = ((m1.z != 0) || (T[jj4 + 2][ii] != 0)) ? 1 : 0;
  o.w = ((m1.w != 0) || (T[jj4 + 3][ii] != 0)) ? 1 : 0;
  *(uchar4*)&msym[bO + (size_t)(i0 + ii) * S_ + j0 + jj4] = o;
}

// ---------------- x fp32 -> bf16 ----------------
__global__ __launch_bounds__(256) void cvt_x_kernel(const float* __restrict__ x,
                                                    unsigned short* __restrict__ o) {
  const size_t i = ((size_t)blockIdx.x * 256 + threadIdx.x) * 8;
  const float4 a = *(const float4*)(x + i);
  const float4 b = *(const float4*)(x + i + 4);
  const ushort4 p0 = {f2bf(a.x), f2bf(a.y), f2bf(a.z), f2bf(a.w)};
  const ushort4 p1 = {f2bf(b.x), f2bf(b.y), f2bf(b.z), f2bf(b.w)};
  *(ushort4*)(o + i) = p0;
  *(ushort4*)(o + i + 4) = p1;
}

// -------- W fp32 [k][n] -> Wt bf16 [n][k], both mats stacked: Wt[2048][1024] --------
__global__ __launch_bounds__(256) void wt_kernel(const float* __restrict__ Wq,
                                                 const float* __restrict__ Wk,
                                                 unsigned short* __restrict__ Wt) {
  const int blk = blockIdx.x;            // 2 * 32 * 32
  const int mat = blk >> 10;
  const int kt = (blk >> 5) & 31, ntb = blk & 31;
  const float* W = mat ? Wk : Wq;
  __shared__ unsigned short T[32][36];
  const int tid = threadIdx.x;
  const int r = tid >> 3, c4 = (tid & 7) << 2;
  const float4 v = *(const float4*)&W[(size_t)(kt * 32 + r) * 1024 + ntb * 32 + c4];
  T[r][c4 + 0] = f2bf(v.x); T[r][c4 + 1] = f2bf(v.y);
  T[r][c4 + 2] = f2bf(v.z); T[r][c4 + 3] = f2bf(v.w);
  __syncthreads();
  const ushort4 o = {T[c4 + 0][r], T[c4 + 1][r], T[c4 + 2][r], T[c4 + 3][r]};
  *(ushort4*)&Wt[(size_t)(mat * 1024 + ntb * 32 + r) * 1024 + kt * 32 + c4] = o;
}

// ------- bf16 MFMA GEMM: P[4096][nstride] = xbf[4096][1024] @ Wt^T (Wt is [n][k]) -----
__global__ __launch_bounds__(256) void gemm_mfma_kernel(const unsigned short* __restrict__ Abf,
                                                        const unsigned short* __restrict__ Wt,
                                                        unsigned short* __restrict__ P,
                                                        int nstride) {
  __shared__ __align__(16) unsigned short As[128 * 32];
  __shared__ __align__(16) unsigned short Bs[128 * 32];
  const int tid = threadIdx.x;
  const int m0 = (blockIdx.x & 31) << 7;
  const int n0 = (blockIdx.x >> 5) << 7;
  const int wave = tid >> 6, lane = tid & 63;
  const int ln15 = lane & 15, rg = lane >> 4;
  const int wm = (wave & 1) << 6;
  const int wn = (wave >> 1) << 6;
  const int sr = tid >> 2;
  const int sc = (tid & 3) << 3;
  const unsigned short* gA = Abf + (size_t)(m0 + sr) * 1024 + sc;
  const unsigned short* gB = Wt + (size_t)(n0 + sr) * 1024 + sc;
  unsigned short* lA = As + tid * 8;
  unsigned short* lB = Bs + tid * 8;
  f32x4 acc[4][4];
#pragma unroll
  for (int i = 0; i < 4; ++i)
#pragma unroll
    for (int j = 0; j < 4; ++j) acc[i][j] = (f32x4){0.0f, 0.0f, 0.0f, 0.0f};

  const unsigned short* pa = As + (wm + ln15) * 32 + rg * 8;
  const unsigned short* pb = Bs + (wn + ln15) * 32 + rg * 8;
  for (int k0 = 0; k0 < E_; k0 += 32) {
    GL2LDS16(gA + k0, lA);
    GL2LDS16(gA + k0 + (size_t)64 * 1024, lA + 2048);
    GL2LDS16(gB + k0, lB);
    GL2LDS16(gB + k0 + (size_t)64 * 1024, lB + 2048);
    __syncthreads();
    short8 af[4], bfr[4];
#pragma unroll
    for (int i = 0; i < 4; ++i) af[i] = *(const short8*)(pa + i * 16 * 32);
#pragma unroll
    for (int j = 0; j < 4; ++j) bfr[j] = *(const short8*)(pb + j * 16 * 32);
#pragma unroll
    for (int i = 0; i < 4; ++i)
#pragma unroll
      for (int j = 0; j < 4; ++j)
        acc[i][j] = __builtin_amdgcn_mfma_f32_16x16x32_bf16(af[i], bfr[j], acc[i][j], 0, 0, 0);
    __syncthreads();
  }
#pragma unroll
  for (int i = 0; i < 4; ++i)
#pragma unroll
    for (int j = 0; j < 4; ++j)
#pragma unroll
      for (int r = 0; r < 4; ++r) {
        const int row = m0 + wm + i * 16 + rg * 4 + r;
        const int col = n0 + wn + j * 16 + ln15;
        P[(size_t)row * nstride + col] = f2bf(acc[i][j][r]);
      }
}

// ------- bias + LayerNorm + ReLU from bf16 P; emit bf16 head-major [b*16+h][s][d] -------
__global__ __launch_bounds__(256) void ln_relu_bf_kernel(const unsigned short* __restrict__ P,
                                                         int rowstride, int coloff,
                                                         const float* __restrict__ bias,
                                                         const float* __restrict__ gamma,
                                                         const float* __restrict__ beta,
                                                         unsigned short* __restrict__ obf) {
  const int row = blockIdx.x;
  const int b = row >> 10, s = row & 1023;
  const unsigned short* p = P + (size_t)row * rowstride + coloff;
  const int tid = threadIdx.x;
  const ushort4 pv = *(const ushort4*)(p + tid * 4);
  float4 v = {bf2f(pv.x), bf2f(pv.y), bf2f(pv.z), bf2f(pv.w)};
  const float4 bb = ((const float4*)bias)[tid];
  v.x += bb.x; v.y += bb.y; v.z += bb.z; v.w += bb.w;
  float sum = v.x + v.y + v.z + v.w;
  float s2 = v.x * v.x + v.y * v.y + v.z * v.z + v.w * v.w;
#pragma unroll
  for (int off = 32; off >= 1; off >>= 1) {
    sum += __shfl_xor(sum, off);
    s2 += __shfl_xor(s2, off);
  }
  __shared__ float red[2][4];
  const int wave = tid >> 6, lane = tid & 63;
  if (lane == 0) { red[0][wave] = sum; red[1][wave] = s2; }
  __syncthreads();
  sum = red[0][0] + red[0][1] + red[0][2] + red[0][3];
  s2 = red[1][0] + red[1][1] + red[1][2] + red[1][3];
  const float mu = sum * (1.0f / E_);
  const float var = s2 * (1.0f / E_) - mu * mu;
  const float r = rsqrtf(var + 1e-5f);
  const float4 g = ((const float4*)gamma)[tid];
  const float4 bt = ((const float4*)beta)[tid];
  const float o0 = fmaxf((v.x - mu) * r * g.x + bt.x, 0.0f);
  const float o1 = fmaxf((v.y - mu) * r * g.y + bt.y, 0.0f);
  const float o2 = fmaxf((v.z - mu) * r * g.z + bt.z, 0.0f);
  const float o3 = fmaxf((v.w - mu) * r * g.w + bt.w, 0.0f);
  const int h = tid >> 4;
  const int d = (tid & 15) << 2;
  const ushort4 ob = {f2bf(o0), f2bf(o1), f2bf(o2), f2bf(o3)};
  *(ushort4*)&obf[((size_t)(b * H_ + h) * S_ + s) * D_ + d] = ob;
}

// ======== attention, split into two grid-rich kernels over (b, q-tile16, key-slice128) ====
// grid 2048: blk -> b = blk&3 (XCD-pinned), idx = blk>>2: qt = idx&63, ks = idx>>6.
// 256 thr = 4 waves; wave owns 32 keys (2 MFMA j-tiles).
// MFMA 16x16x32 bf16, C-layout: col(key)=lane&15, row(q)=(lane>>4)*4+reg.

// ---- pass A: partial softmax denominators -> Lg[b][h][q] (atomicAdd, pre-zeroed) ----
__global__ __launch_bounds__(256, 4) void lsum_kernel(const unsigned short* __restrict__ Qbf,
                                                      const unsigned short* __restrict__ Kbf,
                                                      const unsigned char* __restrict__ msym,
                                                      float* __restrict__ Lg) {
  __shared__ float l_lds[4][16][16];  // [wave][h][q] 4 KB
  const int tid = threadIdx.x;
  const int wave = tid >> 6, lane = tid & 63;
  const int ln15 = lane & 15, rg = lane >> 4;
  const int blk = blockIdx.x;
  const int b = blk & 3;
  const int idx = blk >> 2;
  const int q0 = (idx & 63) << 4;
  const int k0 = ((idx >> 6) << 7) + (wave << 5);
  // mask bits: mrow[r] bit jt = msym[q0+rg*4+r][k0+jt*16+ln15]
  unsigned int mrow[4] = {0u, 0u, 0u, 0u};
#pragma unroll
  for (int jt = 0; jt < 2; ++jt)
#pragma unroll
    for (int r = 0; r < 4; ++r)
      mrow[r] |= (msym[((size_t)b * S_ + q0 + rg * 4 + r) * S_ + k0 + jt * 16 + ln15] ? 1u : 0u) << jt;

  const size_t bbase = (size_t)b * H_ * S_ * D_;
  const size_t qoff = (size_t)(q0 + ln15) * D_ + rg * 8;
  const size_t koff = (size_t)(k0 + ln15) * D_ + rg * 8;
#pragma unroll 2
  for (int h = 0; h < 16; ++h) {
    const size_t hbase = bbase + (size_t)h * S_ * D_;
    const unsigned short* qp = Qbf + hbase + qoff;
    const short8 a0 = *(const short8*)qp;
    const short8 a1 = *(const short8*)(qp + 32);
    float la[4] = {0.0f, 0.0f, 0.0f, 0.0f};
#pragma unroll
    for (int jt = 0; jt < 2; ++jt) {
      const unsigned short* kp = Kbf + hbase + koff + (size_t)jt * (16 * D_);
      const short8 b0 = *(const short8*)kp;
      const short8 b1 = *(const short8*)(kp + 32);
      f32x4 c = {0.0f, 0.0f, 0.0f, 0.0f};
      c = __builtin_amdgcn_mfma_f32_16x16x32_bf16(a0, b0, c, 0, 0, 0);
      c = __builtin_amdgcn_mfma_f32_16x16x32_bf16(a1, b1, c, 0, 0, 0);
#pragma unroll
      for (int r = 0; r < 4; ++r) {
        const float s = fminf(c[r] * 0.125f, 80.0f);
        la[r] += ((mrow[r] >> jt) & 1u) ? 0.0f : __expf(s);
      }
    }
#pragma unroll
    for (int r = 0; r < 4; ++r) {
      float lv = la[r];
      lv += __shfl_xor(lv, 1);
      lv += __shfl_xor(lv, 2);
      lv += __shfl_xor(lv, 4);
      lv += __shfl_xor(lv, 8);
      la[r] = lv;
    }
    if (ln15 == 0) {
      const float4 lw = {la[0], la[1], la[2], la[3]};
      *(float4*)&l_lds[wave][h][rg * 4] = lw;
    }
  }
  __syncthreads();
  // one atomic per (h,q) cell
  {
    const int h = tid >> 4, q = tid & 15;
    const float s = l_lds[0][h][q] + l_lds[1][h][q] + l_lds[2][h][q] + l_lds[3][h][q];
    atomicAdd(&Lg[(((size_t)b * H_ + h) << 10) + q0 + q], s);
  }
}

// ---- pass B: recompute exp, scale by 1/(16*l), head-sum in regs, coalesced store ----
__global__ __launch_bounds__(256, 4) void emit_kernel(const unsigned short* __restrict__ Qbf,
                                                      const unsigned short* __restrict__ Kbf,
                                                      const unsigned char* __restrict__ msym,
                                                      const float* __restrict__ Lg,
                                                      float* __restrict__ out) {
  __shared__ float ob[16][132];  // 8.25 KB, +4 pad
  const int tid = threadIdx.x;
  const int wave = tid >> 6, lane = tid & 63;
  const int ln15 = lane & 15, rg = lane >> 4;
  const int blk = blockIdx.x;
  const int b = blk & 3;
  const int idx = blk >> 2;
  const int q0 = (idx & 63) << 4;
  const int ks = idx >> 6;
  const int k0 = (ks << 7) + (wave << 5);
  unsigned int mrow[4] = {0u, 0u, 0u, 0u};
#pragma unroll
  for (int jt = 0; jt < 2; ++jt)
#pragma unroll
    for (int r = 0; r < 4; ++r)
      mrow[r] |= (msym[((size_t)b * S_ + q0 + rg * 4 + r) * S_ + k0 + jt * 16 + ln15] ? 1u : 0u) << jt;

  const size_t bbase = (size_t)b * H_ * S_ * D_;
  const size_t qoff = (size_t)(q0 + ln15) * D_ + rg * 8;
  const size_t koff = (size_t)(k0 + ln15) * D_ + rg * 8;
  float o[2][4] = {};
#pragma unroll 2
  for (int h = 0; h < 16; ++h) {
    const size_t hbase = bbase + (size_t)h * S_ * D_;
    const unsigned short* qp = Qbf + hbase + qoff;
    const short8 a0 = *(const short8*)qp;
    const short8 a1 = *(const short8*)(qp + 32);
    const float4 l4 = *(const float4*)&Lg[(((size_t)b * H_ + h) << 10) + q0 + rg * 4];
    float li[4];
#pragma unroll
    for (int r = 0; r < 4; ++r) li[r] = 0.0625f * __builtin_amdgcn_rcpf((&l4.x)[r]);
#pragma unroll
    for (int jt = 0; jt < 2; ++jt) {
      const unsigned short* kp = Kbf + hbase + koff + (size_t)jt * (16 * D_);
      const short8 b0 = *(const short8*)kp;
      const short8 b1 = *(const short8*)(kp + 32);
      f32x4 c = {0.0f, 0.0f, 0.0f, 0.0f};
      c = __builtin_amdgcn_mfma_f32_16x16x32_bf16(a0, b0, c, 0, 0, 0);
      c = __builtin_amdgcn_mfma_f32_16x16x32_bf16(a1, b1, c, 0, 0, 0);
#pragma unroll
      for (int r = 0; r < 4; ++r) {
        const float s = fminf(c[r] * 0.125f, 80.0f);
        const float e = ((mrow[r] >> jt) & 1u) ? 0.0f : __expf(s);
        o[jt][r] += e * li[r];
      }
    }
  }
#pragma unroll
  for (int jt = 0; jt < 2; ++jt)
#pragma unroll
    for (int r = 0; r < 4; ++r)
      ob[rg * 4 + r][(wave << 5) + jt * 16 + ln15] = o[jt][r];
  __syncthreads();
  {
    const int row = tid >> 4, c8 = (tid & 15) << 3;
    float* dst = out + ((size_t)b * S_ + q0 + row) * S_ + (ks << 7) + c8;
    *(float4*)dst = *(const float4*)&ob[row][c8];
    *(float4*)(dst + 4) = *(const float4*)&ob[row][c8 + 4];
  }
}

extern "C" void kernel_launch(void* const* d_in, const int* in_sizes, int n_in,
                              void* d_out, int out_size, void* d_ws, size_t ws_size,
                              hipStream_t stream) {
  const float* x = (const float*)d_in[0];
  const int* mask = (const int*)d_in[1];
  const float* Wq = (const float*)d_in[2];
  const float* bq = (const float*)d_in[3];
  const float* Wk = (const float*)d_in[4];
  const float* bk = (const float*)d_in[5];
  const float* gq = (const float*)d_in[6];
  const float* bq_n = (const float*)d_in[7];
  const float* gk = (const float*)d_in[8];
  const float* bk_n = (const float*)d_in[9];
  float* out = (float*)d_out;

  char* ws = (char*)d_ws;
  const size_t MB = 1024 * 1024;

  if (ws_size >= 40 * MB) {
    // fused layout (40 MB): P2 bf16 [4096][2048] @0 (16), xbf @16 (8, Kbf aliases),
    // Wt @24 (4, Lg aliases after gemm), Qbf @28 (8), msym @36 (4)
    unsigned short* P2 = (unsigned short*)ws;
    unsigned short* xbf = (unsigned short*)(ws + 16 * MB);
    unsigned short* Kbf = (unsigned short*)(ws + 16 * MB);   // alias: xbf dead after gemm
    unsigned short* Wt = (unsigned short*)(ws + 24 * MB);
    float* Lg = (float*)(ws + 24 * MB);                      // alias: Wt dead after gemm
    unsigned short* Qbf = (unsigned short*)(ws + 28 * MB);
    unsigned char* msym = (unsigned char*)(ws + 36 * MB);

    mask_sym_kernel<<<4096, 256, 0, stream>>>(mask, msym);
    cvt_x_kernel<<<2048, 256, 0, stream>>>(x, xbf);
    wt_kernel<<<2048, 256, 0, stream>>>(Wq, Wk, Wt);
    gemm_mfma_kernel<<<512, 256, 0, stream>>>(xbf, Wt, P2, 2048);
    ln_relu_bf_kernel<<<4096, 256, 0, stream>>>(P2, 2048, 0, bq, gq, bq_n, Qbf);
    ln_relu_bf_kernel<<<4096, 256, 0, stream>>>(P2, 2048, 1024, bk, gk, bk_n, Kbf);
    hipMemsetAsync(Lg, 0, (size_t)B_ * H_ * S_ * sizeof(float), stream);
    lsum_kernel<<<2048, 256, 0, stream>>>(Qbf, Kbf, msym, Lg);
    emit_kernel<<<2048, 256, 0, stream>>>(Qbf, Kbf, msym, Lg, out);
  } else {
    // split layout (32 MB): P bf16 [4096][1024] @0 (8), xbf @8 (8, Kbf aliases),
    // Wt @16 (4, Lg aliases after 2nd gemm), Qbf @20 (8), msym @28 (4)
    unsigned short* P = (unsigned short*)ws;
    unsigned short* xbf = (unsigned short*)(ws + 8 * MB);
    unsigned short* Kbf = (unsigned short*)(ws + 8 * MB);    // alias: xbf dead after 2nd gemm
    unsigned short* Wt = (unsigned short*)(ws + 16 * MB);
    float* Lg = (float*)(ws + 16 * MB);                      // alias: Wt dead after 2nd gemm
    unsigned short* Qbf = (unsigned short*)(ws + 20 * MB);
    unsigned char* msym = (unsigned char*)(ws + 28 * MB);

    mask_sym_kernel<<<4096, 256, 0, stream>>>(mask, msym);
    cvt_x_kernel<<<2048, 256, 0, stream>>>(x, xbf);
    wt_kernel<<<2048, 256, 0, stream>>>(Wq, Wk, Wt);
    gemm_mfma_kernel<<<256, 256, 0, stream>>>(xbf, Wt, P, 1024);
    ln_relu_bf_kernel<<<4096, 256, 0, stream>>>(P, 1024, 0, bq, gq, bq_n, Qbf);
    gemm_mfma_kernel<<<256, 256, 0, stream>>>(xbf, Wt + (size_t)1024 * 1024, P, 1024);
    ln_relu_bf_kernel<<<4096, 256, 0, stream>>>(P, 1024, 0, bk, gk, bk_n, Kbf);
    hipMemsetAsync(Lg, 0, (size_t)B_ * H_ * S_ * sizeof(float), stream);
    lsum_kernel<<<2048, 256, 0, stream>>>(Qbf, Kbf, msym, Lg);
    emit_kernel<<<2048, 256, 0, stream>>>(Qbf, Kbf, msym, Lg, out);
  }
}

// Round 6
// 227.844 us; speedup vs baseline: 1.4053x; 1.4053x over previous
//
#include <hip/hip_runtime.h>
#include <hip/hip_bf16.h>

#define B_ 4
#define S_ 1024
#define E_ 1024
#define H_ 16
#define D_ 64

typedef __attribute__((ext_vector_type(8))) short short8;
typedef __attribute__((ext_vector_type(4))) float f32x4;

static __device__ __forceinline__ unsigned short f2bf(float x) {
  unsigned int u = __float_as_uint(x);
  unsigned int r = u + 0x7fffu + ((u >> 16) & 1u);  // round-to-nearest-even
  return (unsigned short)(r >> 16);
}
static __device__ __forceinline__ float bf2f(unsigned short b) {
  return __uint_as_float((unsigned int)b << 16);
}

#define GL2LDS16(g, l)                                                            \
  __builtin_amdgcn_global_load_lds(                                               \
      (const __attribute__((address_space(1))) unsigned int*)(g),                 \
      (__attribute__((address_space(3))) unsigned int*)(l), 16, 0, 0)

// ---------------- mask symmetrize: msym = mask | mask^T (uint8) ----------------
__global__ __launch_bounds__(256) void mask_sym_kernel(const int* __restrict__ mask,
                                                       unsigned char* __restrict__ msym) {
  const int blk = blockIdx.x;            // B * 32 * 32 = 4096
  const int b = blk >> 10;
  const int rest = blk & 1023;
  const int i0 = (rest >> 5) << 5;
  const int j0 = (rest & 31) << 5;
  __shared__ int T[32][33];
  const int tid = threadIdx.x;
  const int ii = tid >> 3;
  const int jj4 = (tid & 7) << 2;
  const size_t bO = (size_t)b * S_ * S_;
  const int4 m2 = *(const int4*)&mask[bO + (size_t)(j0 + ii) * S_ + i0 + jj4];
  T[ii][jj4 + 0] = m2.x; T[ii][jj4 + 1] = m2.y; T[ii][jj4 + 2] = m2.z; T[ii][jj4 + 3] = m2.w;
  __syncthreads();
  const int4 m1 = *(const int4*)&mask[bO + (size_t)(i0 + ii) * S_ + j0 + jj4];
  uchar4 o;
  o.x = ((m1.x != 0) || (T[jj4 + 0][ii] != 0)) ? 1 : 0;
  o.y = ((m1.y != 0) || (T[jj4 + 1][ii] != 0)) ? 1 : 0;
  o.z = ((m1.z != 0) || (T[jj4 + 2][ii] != 0)) ? 1 : 0;
  o.w = ((m1.w != 0) || (T[jj4 + 3][ii] != 0)) ? 1 : 0;
  *(uchar4*)&msym[bO + (size_t)(i0 + ii) * S_ + j0 + jj4] = o;
}

// ---------------- x fp32 -> bf16 ----------------
__global__ __launch_bounds__(256) void cvt_x_kernel(const float* __restrict__ x,
                                                    unsigned short* __restrict__ o) {
  const size_t i = ((size_t)blockIdx.x * 256 + threadIdx.x) * 8;
  const float4 a = *(const float4*)(x + i);
  const float4 b = *(const float4*)(x + i + 4);
  const ushort4 p0 = {f2bf(a.x), f2bf(a.y), f2bf(a.z), f2bf(a.w)};
  const ushort4 p1 = {f2bf(b.x), f2bf(b.y), f2bf(b.z), f2bf(b.w)};
  *(ushort4*)(o + i) = p0;
  *(ushort4*)(o + i + 4) = p1;
}

// -------- W fp32 [k][n] -> Wt bf16 [n][k], both mats stacked: Wt[2048][1024] --------
__global__ __launch_bounds__(256) void wt_kernel(const float* __restrict__ Wq,
                                                 const float* __restrict__ Wk,
                                                 unsigned short* __restrict__ Wt) {
  const int blk = blockIdx.x;            // 2 * 32 * 32
  const int mat = blk >> 10;
  const int kt = (blk >> 5) & 31, ntb = blk & 31;
  const float* W = mat ? Wk : Wq;
  __shared__ unsigned short T[32][36];
  const int tid = threadIdx.x;
  const int r = tid >> 3, c4 = (tid & 7) << 2;
  const float4 v = *(const float4*)&W[(size_t)(kt * 32 + r) * 1024 + ntb * 32 + c4];
  T[r][c4 + 0] = f2bf(v.x); T[r][c4 + 1] = f2bf(v.y);
  T[r][c4 + 2] = f2bf(v.z); T[r][c4 + 3] = f2bf(v.w);
  __syncthreads();
  const ushort4 o = {T[c4 + 0][r], T[c4 + 1][r], T[c4 + 2][r], T[c4 + 3][r]};
  *(ushort4*)&Wt[(size_t)(mat * 1024 + ntb * 32 + r) * 1024 + kt * 32 + c4] = o;
}

// ------- bf16 MFMA GEMM: P[4096][nstride] = xbf[4096][1024] @ Wt^T (Wt is [n][k]) -----
__global__ __launch_bounds__(256) void gemm_mfma_kernel(const unsigned short* __restrict__ Abf,
                                                        const unsigned short* __restrict__ Wt,
                                                        unsigned short* __restrict__ P,
                                                        int nstride) {
  __shared__ __align__(16) unsigned short As[128 * 32];
  __shared__ __align__(16) unsigned short Bs[128 * 32];
  const int tid = threadIdx.x;
  const int m0 = (blockIdx.x & 31) << 7;
  const int n0 = (blockIdx.x >> 5) << 7;
  const int wave = tid >> 6, lane = tid & 63;
  const int ln15 = lane & 15, rg = lane >> 4;
  const int wm = (wave & 1) << 6;
  const int wn = (wave >> 1) << 6;
  const int sr = tid >> 2;
  const int sc = (tid & 3) << 3;
  const unsigned short* gA = Abf + (size_t)(m0 + sr) * 1024 + sc;
  const unsigned short* gB = Wt + (size_t)(n0 + sr) * 1024 + sc;
  unsigned short* lA = As + tid * 8;
  unsigned short* lB = Bs + tid * 8;
  f32x4 acc[4][4];
#pragma unroll
  for (int i = 0; i < 4; ++i)
#pragma unroll
    for (int j = 0; j < 4; ++j) acc[i][j] = (f32x4){0.0f, 0.0f, 0.0f, 0.0f};

  const unsigned short* pa = As + (wm + ln15) * 32 + rg * 8;
  const unsigned short* pb = Bs + (wn + ln15) * 32 + rg * 8;
  for (int k0 = 0; k0 < E_; k0 += 32) {
    GL2LDS16(gA + k0, lA);
    GL2LDS16(gA + k0 + (size_t)64 * 1024, lA + 2048);
    GL2LDS16(gB + k0, lB);
    GL2LDS16(gB + k0 + (size_t)64 * 1024, lB + 2048);
    __syncthreads();
    short8 af[4], bfr[4];
#pragma unroll
    for (int i = 0; i < 4; ++i) af[i] = *(const short8*)(pa + i * 16 * 32);
#pragma unroll
    for (int j = 0; j < 4; ++j) bfr[j] = *(const short8*)(pb + j * 16 * 32);
#pragma unroll
    for (int i = 0; i < 4; ++i)
#pragma unroll
      for (int j = 0; j < 4; ++j)
        acc[i][j] = __builtin_amdgcn_mfma_f32_16x16x32_bf16(af[i], bfr[j], acc[i][j], 0, 0, 0);
    __syncthreads();
  }
#pragma unroll
  for (int i = 0; i < 4; ++i)
#pragma unroll
    for (int j = 0; j < 4; ++j)
#pragma unroll
      for (int r = 0; r < 4; ++r) {
        const int row = m0 + wm + i * 16 + rg * 4 + r;
        const int col = n0 + wn + j * 16 + ln15;
        P[(size_t)row * nstride + col] = f2bf(acc[i][j][r]);
      }
}

// ------- bias + LayerNorm + ReLU from bf16 P; emit bf16 head-major [b*16+h][s][d] -------
__global__ __launch_bounds__(256) void ln_relu_bf_kernel(const unsigned short* __restrict__ P,
                                                         int rowstride, int coloff,
                                                         const float* __restrict__ bias,
                                                         const float* __restrict__ gamma,
                                                         const float* __restrict__ beta,
                                                         unsigned short* __restrict__ obf) {
  const int row = blockIdx.x;
  const int b = row >> 10, s = row & 1023;
  const unsigned short* p = P + (size_t)row * rowstride + coloff;
  const int tid = threadIdx.x;
  const ushort4 pv = *(const ushort4*)(p + tid * 4);
  float4 v = {bf2f(pv.x), bf2f(pv.y), bf2f(pv.z), bf2f(pv.w)};
  const float4 bb = ((const float4*)bias)[tid];
  v.x += bb.x; v.y += bb.y; v.z += bb.z; v.w += bb.w;
  float sum = v.x + v.y + v.z + v.w;
  float s2 = v.x * v.x + v.y * v.y + v.z * v.z + v.w * v.w;
#pragma unroll
  for (int off = 32; off >= 1; off >>= 1) {
    sum += __shfl_xor(sum, off);
    s2 += __shfl_xor(s2, off);
  }
  __shared__ float red[2][4];
  const int wave = tid >> 6, lane = tid & 63;
  if (lane == 0) { red[0][wave] = sum; red[1][wave] = s2; }
  __syncthreads();
  sum = red[0][0] + red[0][1] + red[0][2] + red[0][3];
  s2 = red[1][0] + red[1][1] + red[1][2] + red[1][3];
  const float mu = sum * (1.0f / E_);
  const float var = s2 * (1.0f / E_) - mu * mu;
  const float r = rsqrtf(var + 1e-5f);
  const float4 g = ((const float4*)gamma)[tid];
  const float4 bt = ((const float4*)beta)[tid];
  const float o0 = fmaxf((v.x - mu) * r * g.x + bt.x, 0.0f);
  const float o1 = fmaxf((v.y - mu) * r * g.y + bt.y, 0.0f);
  const float o2 = fmaxf((v.z - mu) * r * g.z + bt.z, 0.0f);
  const float o3 = fmaxf((v.w - mu) * r * g.w + bt.w, 0.0f);
  const int h = tid >> 4;
  const int d = (tid & 15) << 2;
  const ushort4 ob = {f2bf(o0), f2bf(o1), f2bf(o2), f2bf(o3)};
  *(ushort4*)&obf[((size_t)(b * H_ + h) * S_ + s) * D_ + d] = ob;
}

// ======= fused attention, single pass: e cached in registers, no atomics =======
// block: (b, 16-q tile), grid 256, 1024 thr = 16 waves; wave owns 64 keys (4 j-tiles).
// Heads in 4 chunks of 4: per chunk compute e (packed bf16 in 32 VGPRs) + partial l,
// LDS cross-wave reduce of l, then scale by 1/(16*l) and head-sum into o[4][4] regs.
// Each (q,k) cell owned by one lane -> plain stores.
// MFMA 16x16x32 bf16, C-layout: col(key)=lane&15, row(q)=(lane>>4)*4+reg.
__global__ __launch_bounds__(1024, 4) void attn4_kernel(const unsigned short* __restrict__ Qbf,
                                                        const unsigned short* __restrict__ Kbf,
                                                        const unsigned char* __restrict__ msym,
                                                        float* __restrict__ out) {
  __shared__ __align__(16) float outAcc[16][1028];  // 64.25 KB, +4 pad -> 2-way (free)
  __shared__ __align__(16) float l_lds[16][4][16];  // [wave][hh][q] 4 KB
  __shared__ __align__(16) float linv_lds[4][16];   // [hh][q]
  const int tid = threadIdx.x;
  const int wave = tid >> 6, lane = tid & 63;
  const int ln15 = lane & 15, rg = lane >> 4;
  const int blk = blockIdx.x;
  const int b = blk & 3;                  // XCD swizzle: K[b] L2-resident per XCD pair
  const int q0 = (blk >> 2) << 4;
  const int k0 = wave << 6;               // 64 keys per wave

  // mask bits: bit (jt*4+r) = msym[q0+rg*4+r][k0+jt*16+ln15]
  unsigned int mbits = 0;
#pragma unroll
  for (int jt = 0; jt < 4; ++jt)
#pragma unroll
    for (int r = 0; r < 4; ++r)
      mbits |= (msym[((size_t)b * S_ + q0 + rg * 4 + r) * S_ + k0 + jt * 16 + ln15] ? 1u : 0u)
               << (jt * 4 + r);

  const size_t bbase = (size_t)b * H_ * S_ * D_;
  const size_t qoff = (size_t)(q0 + ln15) * D_ + rg * 8;
  const size_t koff = (size_t)(k0 + ln15) * D_ + rg * 8;

  float o[4][4] = {};
#pragma unroll 1
  for (int c = 0; c < 4; ++c) {
    unsigned int epack[4][4][2];
    // ---- phase A: e + partial l for 4 heads over this wave's 64 keys ----
#pragma unroll
    for (int hh = 0; hh < 4; ++hh) {
      const size_t hbase = bbase + (size_t)(c * 4 + hh) * S_ * D_;
      const unsigned short* qp = Qbf + hbase + qoff;
      const short8 a0 = *(const short8*)qp;
      const short8 a1 = *(const short8*)(qp + 32);
      const unsigned short* kp = Kbf + hbase + koff;
      float la[4] = {0.0f, 0.0f, 0.0f, 0.0f};
#pragma unroll
      for (int jt = 0; jt < 4; ++jt) {
        const unsigned short* kpj = kp + (size_t)jt * (16 * D_);
        const short8 b0 = *(const short8*)kpj;
        const short8 b1 = *(const short8*)(kpj + 32);
        f32x4 cc = {0.0f, 0.0f, 0.0f, 0.0f};
        cc = __builtin_amdgcn_mfma_f32_16x16x32_bf16(a0, b0, cc, 0, 0, 0);
        cc = __builtin_amdgcn_mfma_f32_16x16x32_bf16(a1, b1, cc, 0, 0, 0);
        float e[4];
#pragma unroll
        for (int r = 0; r < 4; ++r) {
          const float s = fminf(cc[r] * 0.125f, 80.0f);
          e[r] = ((mbits >> (jt * 4 + r)) & 1u) ? 0.0f : __expf(s);
          la[r] += e[r];
        }
        epack[hh][jt][0] = (unsigned)f2bf(e[0]) | ((unsigned)f2bf(e[1]) << 16);
        epack[hh][jt][1] = (unsigned)f2bf(e[2]) | ((unsigned)f2bf(e[3]) << 16);
      }
#pragma unroll
      for (int r = 0; r < 4; ++r) {
        float lv = la[r];
        lv += __shfl_xor(lv, 1);
        lv += __shfl_xor(lv, 2);
        lv += __shfl_xor(lv, 4);
        lv += __shfl_xor(lv, 8);
        la[r] = lv;
      }
      if (ln15 == 0) {
        const float4 lw = {la[0], la[1], la[2], la[3]};
        *(float4*)&l_lds[wave][hh][rg * 4] = lw;
      }
    }
    __syncthreads();
    if (tid < 64) {
      const int hh = tid >> 4, q = tid & 15;
      float s = 0.0f;
#pragma unroll
      for (int w = 0; w < 16; ++w) s += l_lds[w][hh][q];
      linv_lds[hh][q] = 0.0625f / s;
    }
    __syncthreads();
    // ---- phase B: unpack, scale, head-sum in registers (no loads, no recompute) ----
#pragma unroll
    for (int hh = 0; hh < 4; ++hh) {
      const float4 li4 = *(const float4*)&linv_lds[hh][rg * 4];
#pragma unroll
      for (int jt = 0; jt < 4; ++jt) {
        const unsigned u0 = epack[hh][jt][0], u1 = epack[hh][jt][1];
        o[jt][0] += __uint_as_float(u0 << 16) * li4.x;
        o[jt][1] += __uint_as_float(u0 & 0xFFFF0000u) * li4.y;
        o[jt][2] += __uint_as_float(u1 << 16) * li4.z;
        o[jt][3] += __uint_as_float(u1 & 0xFFFF0000u) * li4.w;
      }
    }
    // safety: next chunk's l_lds/linv writes happen only after the next __syncthreads(),
    // which every wave reaches only after finishing this phase B. no hazard.
  }
#pragma unroll
  for (int jt = 0; jt < 4; ++jt)
#pragma unroll
    for (int r = 0; r < 4; ++r)
      outAcc[rg * 4 + r][k0 + jt * 16 + ln15] = o[jt][r];
  __syncthreads();
  {
    const int row = tid >> 6, c0 = (tid & 63) << 4;
    float* dst = out + ((size_t)b * S_ + q0 + row) * S_ + c0;
    const float* srcA = &outAcc[row][c0];
#pragma unroll
    for (int i = 0; i < 4; ++i)
      *(float4*)(dst + i * 4) = *(const float4*)(srcA + i * 4);
  }
}

extern "C" void kernel_launch(void* const* d_in, const int* in_sizes, int n_in,
                              void* d_out, int out_size, void* d_ws, size_t ws_size,
                              hipStream_t stream) {
  const float* x = (const float*)d_in[0];
  const int* mask = (const int*)d_in[1];
  const float* Wq = (const float*)d_in[2];
  const float* bq = (const float*)d_in[3];
  const float* Wk = (const float*)d_in[4];
  const float* bk = (const float*)d_in[5];
  const float* gq = (const float*)d_in[6];
  const float* bq_n = (const float*)d_in[7];
  const float* gk = (const float*)d_in[8];
  const float* bk_n = (const float*)d_in[9];
  float* out = (float*)d_out;

  char* ws = (char*)d_ws;
  const size_t MB = 1024 * 1024;

  if (ws_size >= 40 * MB) {
    // fused layout (40 MB): P2 bf16 [4096][2048] @0 (16), xbf @16 (8, Kbf aliases),
    // Wt @24 (4), Qbf @28 (8), msym @36 (4)
    unsigned short* P2 = (unsigned short*)ws;
    unsigned short* xbf = (unsigned short*)(ws + 16 * MB);
    unsigned short* Kbf = (unsigned short*)(ws + 16 * MB);   // alias: xbf dead after gemm
    unsigned short* Wt = (unsigned short*)(ws + 24 * MB);
    unsigned short* Qbf = (unsigned short*)(ws + 28 * MB);
    unsigned char* msym = (unsigned char*)(ws + 36 * MB);

    mask_sym_kernel<<<4096, 256, 0, stream>>>(mask, msym);
    cvt_x_kernel<<<2048, 256, 0, stream>>>(x, xbf);
    wt_kernel<<<2048, 256, 0, stream>>>(Wq, Wk, Wt);
    gemm_mfma_kernel<<<512, 256, 0, stream>>>(xbf, Wt, P2, 2048);
    ln_relu_bf_kernel<<<4096, 256, 0, stream>>>(P2, 2048, 0, bq, gq, bq_n, Qbf);
    ln_relu_bf_kernel<<<4096, 256, 0, stream>>>(P2, 2048, 1024, bk, gk, bk_n, Kbf);
    attn4_kernel<<<256, 1024, 0, stream>>>(Qbf, Kbf, msym, out);
  } else {
    // split layout (32 MB): P bf16 [4096][1024] @0 (8), xbf @8 (8, Kbf aliases),
    // Wt @16 (4), Qbf @20 (8), msym @28 (4)
    unsigned short* P = (unsigned short*)ws;
    unsigned short* xbf = (unsigned short*)(ws + 8 * MB);
    unsigned short* Kbf = (unsigned short*)(ws + 8 * MB);    // alias: xbf dead after 2nd gemm
    unsigned short* Wt = (unsigned short*)(ws + 16 * MB);
    unsigned short* Qbf = (unsigned short*)(ws + 20 * MB);
    unsigned char* msym = (unsigned char*)(ws + 28 * MB);

    mask_sym_kernel<<<4096, 256, 0, stream>>>(mask, msym);
    cvt_x_kernel<<<2048, 256, 0, stream>>>(x, xbf);
    wt_kernel<<<2048, 256, 0, stream>>>(Wq, Wk, Wt);
    gemm_mfma_kernel<<<256, 256, 0, stream>>>(xbf, Wt, P, 1024);
    ln_relu_bf_kernel<<<4096, 256, 0, stream>>>(P, 1024, 0, bq, gq, bq_n, Qbf);
    gemm_mfma_kernel<<<256, 256, 0, stream>>>(xbf, Wt + (size_t)1024 * 1024, P, 1024);
    ln_relu_bf_kernel<<<4096, 256, 0, stream>>>(P, 1024, 0, bk, gk, bk_n, Kbf);
    attn4_kernel<<<256, 1024, 0, stream>>>(Qbf, Kbf, msym, out);
  }
}

// Round 7
// 201.649 us; speedup vs baseline: 1.5878x; 1.1299x over previous
//
#include <hip/hip_runtime.h>
#include <hip/hip_bf16.h>

#define B_ 4
#define S_ 1024
#define E_ 1024
#define H_ 16
#define D_ 64

typedef __attribute__((ext_vector_type(8))) short short8;
typedef __attribute__((ext_vector_type(4))) float f32x4;

static __device__ __forceinline__ unsigned short f2bf(float x) {
  unsigned int u = __float_as_uint(x);
  unsigned int r = u + 0x7fffu + ((u >> 16) & 1u);  // round-to-nearest-even
  return (unsigned short)(r >> 16);
}
static __device__ __forceinline__ float bf2f(unsigned short b) {
  return __uint_as_float((unsigned int)b << 16);
}

#define GL2LDS16(g, l)                                                            \
  __builtin_amdgcn_global_load_lds(                                               \
      (const __attribute__((address_space(1))) unsigned int*)(g),                 \
      (__attribute__((address_space(3))) unsigned int*)(l), 16, 0, 0)

// ---------- fused preprocessing: mask|mask^T, x->bf16, W->Wt bf16 ----------
// blocks 0..4095: mask_sym; 4096..6143: cvt_x; 6144..8191: wt transpose
__global__ __launch_bounds__(256) void prep_kernel(const int* __restrict__ mask,
                                                   const float* __restrict__ x,
                                                   const float* __restrict__ Wq,
                                                   const float* __restrict__ Wk,
                                                   unsigned char* __restrict__ msym,
                                                   unsigned short* __restrict__ xbf,
                                                   unsigned short* __restrict__ Wt) {
  __shared__ __align__(16) char u_lds[32 * 33 * 4];
  const int blk = blockIdx.x;
  const int tid = threadIdx.x;
  if (blk < 4096) {
    int (*T)[33] = (int(*)[33])u_lds;
    const int b = blk >> 10;
    const int rest = blk & 1023;
    const int i0 = (rest >> 5) << 5;
    const int j0 = (rest & 31) << 5;
    const int ii = tid >> 3;
    const int jj4 = (tid & 7) << 2;
    const size_t bO = (size_t)b * S_ * S_;
    const int4 m2 = *(const int4*)&mask[bO + (size_t)(j0 + ii) * S_ + i0 + jj4];
    T[ii][jj4 + 0] = m2.x; T[ii][jj4 + 1] = m2.y; T[ii][jj4 + 2] = m2.z; T[ii][jj4 + 3] = m2.w;
    __syncthreads();
    const int4 m1 = *(const int4*)&mask[bO + (size_t)(i0 + ii) * S_ + j0 + jj4];
    uchar4 o;
    o.x = ((m1.x != 0) || (T[jj4 + 0][ii] != 0)) ? 1 : 0;
    o.y = ((m1.y != 0) || (T[jj4 + 1][ii] != 0)) ? 1 : 0;
    o.z = ((m1.z != 0) || (T[jj4 + 2][ii] != 0)) ? 1 : 0;
    o.w = ((m1.w != 0) || (T[jj4 + 3][ii] != 0)) ? 1 : 0;
    *(uchar4*)&msym[bO + (size_t)(i0 + ii) * S_ + j0 + jj4] = o;
  } else if (blk < 6144) {
    const size_t i = ((size_t)(blk - 4096) * 256 + tid) * 8;
    const float4 a = *(const float4*)(x + i);
    const float4 b = *(const float4*)(x + i + 4);
    const ushort4 p0 = {f2bf(a.x), f2bf(a.y), f2bf(a.z), f2bf(a.w)};
    const ushort4 p1 = {f2bf(b.x), f2bf(b.y), f2bf(b.z), f2bf(b.w)};
    *(ushort4*)(xbf + i) = p0;
    *(ushort4*)(xbf + i + 4) = p1;
  } else {
    unsigned short (*T2)[36] = (unsigned short(*)[36])u_lds;
    const int wblk = blk - 6144;           // 2 * 32 * 32
    const int mat = wblk >> 10;
    const int kt = (wblk >> 5) & 31, ntb = wblk & 31;
    const float* W = mat ? Wk : Wq;
    const int r = tid >> 3, c4 = (tid & 7) << 2;
    const float4 v = *(const float4*)&W[(size_t)(kt * 32 + r) * 1024 + ntb * 32 + c4];
    T2[r][c4 + 0] = f2bf(v.x); T2[r][c4 + 1] = f2bf(v.y);
    T2[r][c4 + 2] = f2bf(v.z); T2[r][c4 + 3] = f2bf(v.w);
    __syncthreads();
    const ushort4 o = {T2[c4 + 0][r], T2[c4 + 1][r], T2[c4 + 2][r], T2[c4 + 3][r]};
    *(ushort4*)&Wt[(size_t)(mat * 1024 + ntb * 32 + r) * 1024 + kt * 32 + c4] = o;
  }
}

// ------- bf16 MFMA GEMM: P[4096][nstride] = xbf[4096][1024] @ Wt^T (Wt is [n][k]) -----
__global__ __launch_bounds__(256) void gemm_mfma_kernel(const unsigned short* __restrict__ Abf,
                                                        const unsigned short* __restrict__ Wt,
                                                        unsigned short* __restrict__ P,
                                                        int nstride) {
  __shared__ __align__(16) unsigned short As[128 * 32];
  __shared__ __align__(16) unsigned short Bs[128 * 32];
  const int tid = threadIdx.x;
  const int m0 = (blockIdx.x & 31) << 7;
  const int n0 = (blockIdx.x >> 5) << 7;
  const int wave = tid >> 6, lane = tid & 63;
  const int ln15 = lane & 15, rg = lane >> 4;
  const int wm = (wave & 1) << 6;
  const int wn = (wave >> 1) << 6;
  const int sr = tid >> 2;
  const int sc = (tid & 3) << 3;
  const unsigned short* gA = Abf + (size_t)(m0 + sr) * 1024 + sc;
  const unsigned short* gB = Wt + (size_t)(n0 + sr) * 1024 + sc;
  unsigned short* lA = As + tid * 8;
  unsigned short* lB = Bs + tid * 8;
  f32x4 acc[4][4];
#pragma unroll
  for (int i = 0; i < 4; ++i)
#pragma unroll
    for (int j = 0; j < 4; ++j) acc[i][j] = (f32x4){0.0f, 0.0f, 0.0f, 0.0f};

  const unsigned short* pa = As + (wm + ln15) * 32 + rg * 8;
  const unsigned short* pb = Bs + (wn + ln15) * 32 + rg * 8;
  for (int k0 = 0; k0 < E_; k0 += 32) {
    GL2LDS16(gA + k0, lA);
    GL2LDS16(gA + k0 + (size_t)64 * 1024, lA + 2048);
    GL2LDS16(gB + k0, lB);
    GL2LDS16(gB + k0 + (size_t)64 * 1024, lB + 2048);
    __syncthreads();
    short8 af[4], bfr[4];
#pragma unroll
    for (int i = 0; i < 4; ++i) af[i] = *(const short8*)(pa + i * 16 * 32);
#pragma unroll
    for (int j = 0; j < 4; ++j) bfr[j] = *(const short8*)(pb + j * 16 * 32);
#pragma unroll
    for (int i = 0; i < 4; ++i)
#pragma unroll
      for (int j = 0; j < 4; ++j)
        acc[i][j] = __builtin_amdgcn_mfma_f32_16x16x32_bf16(af[i], bfr[j], acc[i][j], 0, 0, 0);
    __syncthreads();
  }
#pragma unroll
  for (int i = 0; i < 4; ++i)
#pragma unroll
    for (int j = 0; j < 4; ++j)
#pragma unroll
      for (int r = 0; r < 4; ++r) {
        const int row = m0 + wm + i * 16 + rg * 4 + r;
        const int col = n0 + wn + j * 16 + ln15;
        P[(size_t)row * nstride + col] = f2bf(acc[i][j][r]);
      }
}

// ------- bias + LayerNorm + ReLU from bf16 P; emit bf16 head-major [b*16+h][s][d] -------
__global__ __launch_bounds__(256) void ln_relu_bf_kernel(const unsigned short* __restrict__ P,
                                                         int rowstride, int coloff,
                                                         const float* __restrict__ bias,
                                                         const float* __restrict__ gamma,
                                                         const float* __restrict__ beta,
                                                         unsigned short* __restrict__ obf) {
  const int row = blockIdx.x;
  const int b = row >> 10, s = row & 1023;
  const unsigned short* p = P + (size_t)row * rowstride + coloff;
  const int tid = threadIdx.x;
  const ushort4 pv = *(const ushort4*)(p + tid * 4);
  float4 v = {bf2f(pv.x), bf2f(pv.y), bf2f(pv.z), bf2f(pv.w)};
  const float4 bb = ((const float4*)bias)[tid];
  v.x += bb.x; v.y += bb.y; v.z += bb.z; v.w += bb.w;
  float sum = v.x + v.y + v.z + v.w;
  float s2 = v.x * v.x + v.y * v.y + v.z * v.z + v.w * v.w;
#pragma unroll
  for (int off = 32; off >= 1; off >>= 1) {
    sum += __shfl_xor(sum, off);
    s2 += __shfl_xor(s2, off);
  }
  __shared__ float red[2][4];
  const int wave = tid >> 6, lane = tid & 63;
  if (lane == 0) { red[0][wave] = sum; red[1][wave] = s2; }
  __syncthreads();
  sum = red[0][0] + red[0][1] + red[0][2] + red[0][3];
  s2 = red[1][0] + red[1][1] + red[1][2] + red[1][3];
  const float mu = sum * (1.0f / E_);
  const float var = s2 * (1.0f / E_) - mu * mu;
  const float r = rsqrtf(var + 1e-5f);
  const float4 g = ((const float4*)gamma)[tid];
  const float4 bt = ((const float4*)beta)[tid];
  const float o0 = fmaxf((v.x - mu) * r * g.x + bt.x, 0.0f);
  const float o1 = fmaxf((v.y - mu) * r * g.y + bt.y, 0.0f);
  const float o2 = fmaxf((v.z - mu) * r * g.z + bt.z, 0.0f);
  const float o3 = fmaxf((v.w - mu) * r * g.w + bt.w, 0.0f);
  const int h = tid >> 4;
  const int d = (tid & 15) << 2;
  const ushort4 ob = {f2bf(o0), f2bf(o1), f2bf(o2), f2bf(o3)};
  *(ushort4*)&obf[((size_t)(b * H_ + h) * S_ + s) * D_ + d] = ob;
}

// ======= fused attention: head-outer, double-buffered LDS K staging =======
// block: (b, 16-q), grid 256, 1024 thr = 16 waves. Per head: 4 quarter-tiles of 256
// keys staged cooperatively in LDS (double-buffered, register prefetch overlaps
// compute). Wave owns key j-tile (qt*256 + wave*16). e packed bf16 (8 VGPRs/head),
// l via shuffle + LDS cross-wave reduce, o head-summed in 16 regs, direct stores.
// LDS layout: row stride 128 B, chunk XOR-swizzle p = c ^ (row&7) -> 16B-aligned
// ds_*_b128, bank-balanced for both staging writes and fragment reads.
// MFMA 16x16x32 bf16, C-layout: col(key)=lane&15, row(q)=(lane>>4)*4+reg.
__global__ __launch_bounds__(1024, 4) void attn5_kernel(const unsigned short* __restrict__ Qbf,
                                                        const unsigned short* __restrict__ Kbf,
                                                        const unsigned char* __restrict__ msym,
                                                        float* __restrict__ out) {
  __shared__ __align__(16) unsigned short Qs[256 * 64];     // 32 KB: row = h*16+q
  __shared__ __align__(16) unsigned short Ks[2][256 * 64];  // 64 KB: row = key-in-quarter
  __shared__ __align__(16) float l_lds[16][16];             // [wave][q]
  __shared__ __align__(16) float linv[16];
  const int tid = threadIdx.x;
  const int wave = tid >> 6, lane = tid & 63;
  const int ln15 = lane & 15, rg = lane >> 4;
  const int b = blockIdx.x & 3;                 // XCD swizzle
  const int q0 = (blockIdx.x >> 2) << 4;

  const unsigned short* Kb = Kbf + (size_t)b * H_ * S_ * D_;

  // ---- stage Q[h=0..15][q=0..15][64] (32 KB), swizzled ----
  {
    const int rho = tid >> 3, p = tid & 7;
    const int c = p ^ (rho & 7);
    const int rho2 = rho + 128;
    const int c2 = p ^ (rho2 & 7);  // == c (rho2&7 == rho&7)
    const uint4 v0 = *(const uint4*)(Qbf + ((size_t)(b * H_ + (rho >> 4)) * S_ + q0 + (rho & 15)) * D_ + c * 8);
    const uint4 v1 = *(const uint4*)(Qbf + ((size_t)(b * H_ + (rho2 >> 4)) * S_ + q0 + (rho2 & 15)) * D_ + c2 * 8);
    *(uint4*)&Qs[rho * 64 + p * 8] = v0;
    *(uint4*)&Qs[rho2 * 64 + p * 8] = v1;
  }
  // ---- mask bits: bit(qt*4+r) = msym[q0+rg*4+r][qt*256 + wave*16 + ln15] ----
  unsigned int mbits = 0;
#pragma unroll
  for (int qt = 0; qt < 4; ++qt)
#pragma unroll
    for (int r = 0; r < 4; ++r)
      mbits |= (msym[((size_t)b * S_ + q0 + rg * 4 + r) * S_ + qt * 256 + wave * 16 + ln15] ? 1u : 0u)
               << (qt * 4 + r);

  // ---- staging thread mapping: key rows krow, krow+128; phys chunk kp ----
  const int krow = tid >> 3, kp = tid & 7;
  const int kcc = kp ^ (krow & 7);              // logical chunk for both rows
  // prologue: stage step 0 (h=0, qt=0) into Ks[0]
  {
    const unsigned short* src = Kb + (size_t)krow * D_ + kcc * 8;
    const uint4 p0 = *(const uint4*)src;
    const uint4 p1 = *(const uint4*)(src + 128 * D_);
    *(uint4*)&Ks[0][krow * 64 + kp * 8] = p0;
    *(uint4*)&Ks[0][(krow + 128) * 64 + kp * 8] = p1;
  }
  __syncthreads();

  const int pfrag = (rg ^ (ln15 & 7)) * 8;      // swizzled chunk offset (shorts)
  const unsigned short* QsW = Qs + ln15 * 64;
  const unsigned short* KsW0 = Ks[0] + (wave * 16 + ln15) * 64;
  const unsigned short* KsW1 = Ks[1] + (wave * 16 + ln15) * 64;

  float o[4][4] = {};
  unsigned int epack[4][2];
  uint4 pf0, pf1;

#pragma unroll 1
  for (int h = 0; h < 16; ++h) {
    const unsigned short* qrow = QsW + h * 16 * 64;
    const short8 a0 = *(const short8*)(qrow + pfrag);
    const short8 a1 = *(const short8*)(qrow + (pfrag ^ 32));
    float la[4] = {0.0f, 0.0f, 0.0f, 0.0f};
#pragma unroll
    for (int qt = 0; qt < 4; ++qt) {
      const int s = h * 4 + qt;
      // prefetch step s+1 into registers (latency overlapped by this step's compute)
      if (s < 63) {
        const int s1 = s + 1;
        const unsigned short* src =
            Kb + ((size_t)(s1 >> 2) * S_ + ((s1 & 3) << 8) + krow) * D_ + kcc * 8;
        pf0 = *(const uint4*)src;
        pf1 = *(const uint4*)(src + 128 * D_);
      }
      // compute from current buffer (buf = qt&1 since h*4 is even)
      const unsigned short* kw = (qt & 1) ? KsW1 : KsW0;
      const short8 b0 = *(const short8*)(kw + pfrag);
      const short8 b1 = *(const short8*)(kw + (pfrag ^ 32));
      f32x4 cc = {0.0f, 0.0f, 0.0f, 0.0f};
      cc = __builtin_amdgcn_mfma_f32_16x16x32_bf16(a0, b0, cc, 0, 0, 0);
      cc = __builtin_amdgcn_mfma_f32_16x16x32_bf16(a1, b1, cc, 0, 0, 0);
      float e[4];
#pragma unroll
      for (int r = 0; r < 4; ++r) {
        const float sv = fminf(cc[r] * 0.125f, 80.0f);
        e[r] = ((mbits >> (qt * 4 + r)) & 1u) ? 0.0f : __expf(sv);
        la[r] += e[r];
      }
      epack[qt][0] = (unsigned)f2bf(e[0]) | ((unsigned)f2bf(e[1]) << 16);
      epack[qt][1] = (unsigned)f2bf(e[2]) | ((unsigned)f2bf(e[3]) << 16);
      // commit prefetched tile to the other buffer
      if (s < 63) {
        unsigned short* dst = (qt & 1) ? Ks[0] : Ks[1];
        *(uint4*)&dst[krow * 64 + kp * 8] = pf0;
        *(uint4*)&dst[(krow + 128) * 64 + kp * 8] = pf1;
      }
      if (qt < 3) __syncthreads();
    }
    // head end: reduce l over the 16 key-lanes per q-row, then cross-wave
#pragma unroll
    for (int r = 0; r < 4; ++r) {
      float lv = la[r];
      lv += __shfl_xor(lv, 1);
      lv += __shfl_xor(lv, 2);
      lv += __shfl_xor(lv, 4);
      lv += __shfl_xor(lv, 8);
      la[r] = lv;
    }
    if (ln15 == 0) *(float4*)&l_lds[wave][rg * 4] = (float4){la[0], la[1], la[2], la[3]};
    __syncthreads();   // covers l_lds + next head's K buffer
    if (tid < 16) {
      float ssum = 0.0f;
#pragma unroll
      for (int w = 0; w < 16; ++w) ssum += l_lds[w][tid];
      linv[tid] = 0.0625f / ssum;   // 1/(16*l): head-mean folded in
    }
    __syncthreads();
    const float4 li4 = *(const float4*)&linv[rg * 4];
#pragma unroll
    for (int qt = 0; qt < 4; ++qt) {
      o[qt][0] += __uint_as_float(epack[qt][0] << 16) * li4.x;
      o[qt][1] += __uint_as_float(epack[qt][0] & 0xFFFF0000u) * li4.y;
      o[qt][2] += __uint_as_float(epack[qt][1] << 16) * li4.z;
      o[qt][3] += __uint_as_float(epack[qt][1] & 0xFFFF0000u) * li4.w;
    }
  }
  // direct stores: each 16-lane group writes 64 B contiguous per (qt,r)
#pragma unroll
  for (int qt = 0; qt < 4; ++qt)
#pragma unroll
    for (int r = 0; r < 4; ++r)
      out[((size_t)b * S_ + q0 + rg * 4 + r) * S_ + qt * 256 + wave * 16 + ln15] = o[qt][r];
}

extern "C" void kernel_launch(void* const* d_in, const int* in_sizes, int n_in,
                              void* d_out, int out_size, void* d_ws, size_t ws_size,
                              hipStream_t stream) {
  const float* x = (const float*)d_in[0];
  const int* mask = (const int*)d_in[1];
  const float* Wq = (const float*)d_in[2];
  const float* bq = (const float*)d_in[3];
  const float* Wk = (const float*)d_in[4];
  const float* bk = (const float*)d_in[5];
  const float* gq = (const float*)d_in[6];
  const float* bq_n = (const float*)d_in[7];
  const float* gk = (const float*)d_in[8];
  const float* bk_n = (const float*)d_in[9];
  float* out = (float*)d_out;

  char* ws = (char*)d_ws;
  const size_t MB = 1024 * 1024;

  if (ws_size >= 40 * MB) {
    // fused layout (40 MB): P2 bf16 [4096][2048] @0 (16), xbf @16 (8, Kbf aliases),
    // Wt @24 (4), Qbf @28 (8), msym @36 (4)
    unsigned short* P2 = (unsigned short*)ws;
    unsigned short* xbf = (unsigned short*)(ws + 16 * MB);
    unsigned short* Kbf = (unsigned short*)(ws + 16 * MB);   // alias: xbf dead after gemm
    unsigned short* Wt = (unsigned short*)(ws + 24 * MB);
    unsigned short* Qbf = (unsigned short*)(ws + 28 * MB);
    unsigned char* msym = (unsigned char*)(ws + 36 * MB);

    prep_kernel<<<8192, 256, 0, stream>>>(mask, x, Wq, Wk, msym, xbf, Wt);
    gemm_mfma_kernel<<<512, 256, 0, stream>>>(xbf, Wt, P2, 2048);
    ln_relu_bf_kernel<<<4096, 256, 0, stream>>>(P2, 2048, 0, bq, gq, bq_n, Qbf);
    ln_relu_bf_kernel<<<4096, 256, 0, stream>>>(P2, 2048, 1024, bk, gk, bk_n, Kbf);
    attn5_kernel<<<256, 1024, 0, stream>>>(Qbf, Kbf, msym, out);
  } else {
    // split layout (32 MB): P bf16 [4096][1024] @0 (8), xbf @8 (8, Kbf aliases),
    // Wt @16 (4), Qbf @20 (8), msym @28 (4)
    unsigned short* P = (unsigned short*)ws;
    unsigned short* xbf = (unsigned short*)(ws + 8 * MB);
    unsigned short* Kbf = (unsigned short*)(ws + 8 * MB);    // alias: xbf dead after 2nd gemm
    unsigned short* Wt = (unsigned short*)(ws + 16 * MB);
    unsigned short* Qbf = (unsigned short*)(ws + 20 * MB);
    unsigned char* msym = (unsigned char*)(ws + 28 * MB);

    prep_kernel<<<8192, 256, 0, stream>>>(mask, x, Wq, Wk, msym, xbf, Wt);
    gemm_mfma_kernel<<<256, 256, 0, stream>>>(xbf, Wt, P, 1024);
    ln_relu_bf_kernel<<<4096, 256, 0, stream>>>(P, 1024, 0, bq, gq, bq_n, Qbf);
    gemm_mfma_kernel<<<256, 256, 0, stream>>>(xbf, Wt + (size_t)1024 * 1024, P, 1024);
    ln_relu_bf_kernel<<<4096, 256, 0, stream>>>(P, 1024, 0, bk, gk, bk_n, Kbf);
    attn5_kernel<<<256, 1024, 0, stream>>>(Qbf, Kbf, msym, out);
  }
}